// Round 1
// baseline (332.217 us; speedup 1.0000x reference)
//
#include <hip/hip_runtime.h>
#include <stdint.h>

#define B 64
#define N 32
#define K 16
#define NUM_WORDS 65536

// ws layout: [0..B) unsigned long long packed argmax keys
__global__ void mdd_init(unsigned long long* __restrict__ keys) {
    int i = threadIdx.x;
    if (i < B) keys[i] = 0ULL;
}

__global__ __launch_bounds__(256) void mdd_decode(
    const float* __restrict__ noisy,   // [B][N]
    const int* __restrict__ G,         // [K][N]
    const float* __restrict__ sigma2,  // [1]
    unsigned long long* __restrict__ keys) // [B]
{
    __shared__ uint32_t g_rows[K];
    __shared__ float llr[B * N];

    const int tid = threadIdx.x;

    // Pack G rows into bitmasks: bit n of g_rows[k] = G[k][n] & 1
    if (tid < K) {
        uint32_t r = 0;
        #pragma unroll
        for (int n = 0; n < N; ++n)
            r |= (uint32_t)(G[tid * N + n] & 1) << n;
        g_rows[tid] = r;
    }

    // llr = -4 * noisy / sigma2 (positive/negative scale is irrelevant to the
    // argmax only up to sign; compute exactly as reference to be safe)
    const float scale = -4.0f / sigma2[0];
    for (int i = tid; i < B * N; i += 256)
        llr[i] = scale * noisy[i];

    __syncthreads();

    const uint32_t w = blockIdx.x * 256u + (uint32_t)tid;

    // codeword bits of w: XOR of selected G rows
    uint32_t cw = 0;
    #pragma unroll
    for (int k = 0; k < K; ++k)
        cw ^= g_rows[k] & (0u - ((w >> k) & 1u));

    const int lane = tid & 63;

    for (int b = 0; b < B; ++b) {
        const float* lb = &llr[b * N];
        // corr = sum_n sign_n * llr_n, sign flip via XOR into the f32 sign bit
        float corr = 0.0f;
        #pragma unroll
        for (int n = 0; n < N; ++n) {
            uint32_t fb = __float_as_uint(lb[n]) ^ (((cw >> n) & 1u) << 31);
            corr += __uint_as_float(fb);
        }

        // monotone float->uint map (no NaNs expected)
        uint32_t bits = __float_as_uint(corr);
        uint32_t mono = (bits & 0x80000000u) ? ~bits : (bits | 0x80000000u);
        // key: higher corr wins; among equal corr, smaller w wins (~w larger)
        unsigned long long key =
            ((unsigned long long)mono << 32) | (unsigned long long)(~w);

        // wave-level max reduction (64 lanes)
        #pragma unroll
        for (int off = 32; off > 0; off >>= 1) {
            unsigned long long other = __shfl_xor(key, off, 64);
            key = (other > key) ? other : key;
        }
        if (lane == 0)
            atomicMax(&keys[b], key);
    }
}

__global__ void mdd_final(const unsigned long long* __restrict__ keys,
                          float* __restrict__ out) // [B][K]
{
    int tid = threadIdx.x;           // 1024 threads: b = tid>>4, k = tid&15
    int b = tid >> 4;
    int k = tid & 15;
    uint32_t w = ~(uint32_t)(keys[b] & 0xFFFFFFFFull);
    out[b * K + k] = (float)((w >> k) & 1u);
}

extern "C" void kernel_launch(void* const* d_in, const int* in_sizes, int n_in,
                              void* d_out, int out_size, void* d_ws, size_t ws_size,
                              hipStream_t stream) {
    const float* noisy = (const float*)d_in[0];
    const int* G = (const int*)d_in[1];
    const float* sigma2 = (const float*)d_in[2];
    float* out = (float*)d_out;
    unsigned long long* keys = (unsigned long long*)d_ws;

    (void)in_sizes; (void)n_in; (void)out_size; (void)ws_size;

    mdd_init<<<1, 64, 0, stream>>>(keys);
    mdd_decode<<<NUM_WORDS / 256, 256, 0, stream>>>(noisy, G, sigma2, keys);
    mdd_final<<<1, B * K, 0, stream>>>(keys, out);
}

// Round 2
// 25.818 us; speedup vs baseline: 12.8677x; 12.8677x over previous
//
#include <hip/hip_runtime.h>
#include <stdint.h>

#define B 64
#define N 32
#define K 16
#define NUM_WORDS 65536
#define BLOCKS 512
#define WPB (NUM_WORDS / BLOCKS)   // 128 words per block
#define WPW (WPB / 4)              // 32 words per wave

typedef unsigned long long u64;

static __device__ __forceinline__ u64 umax64(u64 a, u64 b) { return a > b ? a : b; }

// Kernel 1: each block handles WPB words; within a wave, lane l = batch l.
// All lanes process the same word simultaneously (cw broadcast from LDS).
// Per (block, batch) best key written to ws_keys[block*64 + l]. No atomics.
__global__ __launch_bounds__(256) void mdd_corr(
    const float* __restrict__ noisy,   // [B][N]
    const int* __restrict__ G,         // [K][N]
    const float* __restrict__ sigma2,  // [1]
    u64* __restrict__ ws_keys)         // [BLOCKS][B]
{
    __shared__ uint32_t g_rows[K];
    __shared__ uint32_t cw_lds[WPB];
    __shared__ float llr_t[N * B];     // [n][l] transposed: lane-consecutive
    __shared__ u64 bestk[4 * B];

    const int tid = threadIdx.x;

    // Pack G rows into 32-bit masks
    if (tid < K) {
        uint32_t r = 0;
        #pragma unroll
        for (int n = 0; n < N; ++n)
            r |= (uint32_t)(G[tid * N + n] & 1) << n;
        g_rows[tid] = r;
    }
    __syncthreads();

    // Codewords for this block's words: XOR of selected G rows
    if (tid < WPB) {
        uint32_t w = blockIdx.x * WPB + tid;
        uint32_t cw = 0;
        #pragma unroll
        for (int k = 0; k < K; ++k)
            cw ^= g_rows[k] & (0u - ((w >> k) & 1u));
        cw_lds[tid] = cw;
    }

    // llr transposed into LDS (l fastest -> conflict-free ds_writes)
    const float scale = -4.0f / sigma2[0];
    for (int i = tid; i < B * N; i += 256) {
        int l = i & 63, n = i >> 6;
        llr_t[n * B + l] = scale * noisy[l * N + n];
    }
    __syncthreads();

    const int wv = tid >> 6, l = tid & 63;

    // This lane's batch LLRs into registers
    float la[N];
    #pragma unroll
    for (int n = 0; n < N; ++n) la[n] = llr_t[n * B + l];

    u64 best = 0;
    const int wbase = wv * WPW;
    #pragma unroll 4
    for (int wi = 0; wi < WPW; ++wi) {
        const uint32_t cw = cw_lds[wbase + wi];   // wave-uniform broadcast
        float c0 = 0.f, c1 = 0.f, c2 = 0.f, c3 = 0.f;
        #pragma unroll
        for (int n = 0; n < N; n += 4) {
            uint32_t m0 = (cw << (31 - (n + 0))) & 0x80000000u;
            uint32_t m1 = (cw << (31 - (n + 1))) & 0x80000000u;
            uint32_t m2 = (cw << (31 - (n + 2))) & 0x80000000u;
            uint32_t m3 = (cw << (31 - (n + 3))) & 0x80000000u;
            c0 += __uint_as_float(__float_as_uint(la[n + 0]) ^ m0);
            c1 += __uint_as_float(__float_as_uint(la[n + 1]) ^ m1);
            c2 += __uint_as_float(__float_as_uint(la[n + 2]) ^ m2);
            c3 += __uint_as_float(__float_as_uint(la[n + 3]) ^ m3);
        }
        float corr = (c0 + c1) + (c2 + c3);
        // monotone float->uint (no NaNs in this data)
        uint32_t bits = __float_as_uint(corr);
        uint32_t mono = (bits & 0x80000000u) ? ~bits : (bits | 0x80000000u);
        uint32_t w = blockIdx.x * WPB + wbase + wi;
        u64 key = ((u64)mono << 16) | (u64)(0xFFFFu - w);  // ties -> smaller w wins
        best = umax64(best, key);
    }

    bestk[wv * B + l] = best;
    __syncthreads();

    if (tid < B) {
        u64 k = umax64(umax64(bestk[tid], bestk[B + tid]),
                       umax64(bestk[2 * B + tid], bestk[3 * B + tid]));
        ws_keys[blockIdx.x * B + tid] = k;   // coalesced 512B store
    }
}

// Kernel 2: one block per batch; 512-way max over per-block keys, decode word.
__global__ __launch_bounds__(256) void mdd_reduce(
    const u64* __restrict__ ws_keys,   // [BLOCKS][B]
    float* __restrict__ out)           // [B][K]
{
    const int b = blockIdx.x;
    const int t = threadIdx.x;

    u64 k = umax64(ws_keys[t * B + b], ws_keys[(t + 256) * B + b]);

    #pragma unroll
    for (int off = 32; off > 0; off >>= 1) {
        u64 other = __shfl_xor(k, off, 64);
        k = umax64(k, other);
    }

    __shared__ u64 l2[4];
    if ((t & 63) == 0) l2[t >> 6] = k;
    __syncthreads();

    if (t == 0) {
        u64 f = umax64(umax64(l2[0], l2[1]), umax64(l2[2], l2[3]));
        uint32_t w = 0xFFFFu - (uint32_t)(f & 0xFFFFu);
        #pragma unroll
        for (int kk = 0; kk < K; ++kk)
            out[b * K + kk] = (float)((w >> kk) & 1u);
    }
}

extern "C" void kernel_launch(void* const* d_in, const int* in_sizes, int n_in,
                              void* d_out, int out_size, void* d_ws, size_t ws_size,
                              hipStream_t stream) {
    const float* noisy = (const float*)d_in[0];
    const int* G = (const int*)d_in[1];
    const float* sigma2 = (const float*)d_in[2];
    float* out = (float*)d_out;
    u64* ws_keys = (u64*)d_ws;

    (void)in_sizes; (void)n_in; (void)out_size; (void)ws_size;

    mdd_corr<<<BLOCKS, 256, 0, stream>>>(noisy, G, sigma2, ws_keys);
    mdd_reduce<<<B, 256, 0, stream>>>(ws_keys, out);
}

// Round 3
// 13.801 us; speedup vs baseline: 24.0711x; 1.8707x over previous
//
#include <hip/hip_runtime.h>
#include <stdint.h>

#define B 64
#define N 32
#define K 16
#define NUM_WORDS 65536
#define BLOCKS 512
#define WPB 128            // words per block
#define LLR_PAD 65         // padded stride for transpose staging

typedef unsigned long long u64;

// Kernel 1: lane l = batch l; wave processes words together (cw wave-uniform).
// Correlation via per-batch nibble tables in LDS: corr = sum_j T[j][nib_j(cw)][l].
__global__ __launch_bounds__(256) void mdd_corr(
    const float* __restrict__ noisy,   // [B][N]
    const int* __restrict__ G,         // [K][N]
    const float* __restrict__ sigma2,  // [1]
    u64* __restrict__ ws_keys)         // [B][BLOCKS]
{
    __shared__ uint32_t g_rows[K];
    __shared__ __align__(16) uint32_t cw_lds[WPB];
    __shared__ float T_lds[8 * 16 * 64];       // [j][v][lane] 32 KB
    __shared__ float llr_t[N * LLR_PAD];       // [n][b] padded
    __shared__ float bestf_lds[4 * 64];
    __shared__ uint32_t bestw_lds[4 * 64];

    const int tid = threadIdx.x;
    const int l = tid & 63;
    const int wv = tid >> 6;

    // Pack G rows into 32-bit masks (bit n = G[k][n] & 1)
    if (tid < K) {
        uint32_t r = 0;
        #pragma unroll
        for (int n = 0; n < N; ++n)
            r |= (uint32_t)(G[tid * N + n] & 1) << n;
        g_rows[tid] = r;
    }

    // Coalesced load of noisy, transposed into padded LDS: llr_t[n][b]
    const float scale = -4.0f / sigma2[0];
    for (int i = tid; i < B * N; i += 256) {
        int n = i & 31, bb = i >> 5;
        llr_t[n * LLR_PAD + bb] = scale * noisy[i];
    }
    __syncthreads();

    // Codewords for this block's 128 words
    if (tid < WPB) {
        uint32_t w = blockIdx.x * WPB + tid;
        uint32_t cw = 0;
        #pragma unroll
        for (int k = 0; k < K; ++k)
            cw ^= g_rows[k] & (0u - ((w >> k) & 1u));
        cw_lds[tid] = cw;
    }

    // Build nibble tables: task (j, l); thread handles j = wv and wv+4.
    // T[j][v] = s(v0)l0 + s(v1)l1 + s(v2)l2 + s(v3)l3, s(b)=1-2b, as balanced
    // tree of exactly-negated adds (bit-identical for identical codewords).
    for (int j = wv; j < 8; j += 4) {
        float l0 = llr_t[(4 * j + 0) * LLR_PAD + l];
        float l1 = llr_t[(4 * j + 1) * LLR_PAD + l];
        float l2 = llr_t[(4 * j + 2) * LLR_PAD + l];
        float l3 = llr_t[(4 * j + 3) * LLR_PAD + l];
        float A[4] = { l0 + l1, -l0 + l1, l0 - l1, -l0 - l1 };
        float C[4] = { l2 + l3, -l2 + l3, l2 - l3, -l2 - l3 };
        float* Tj = &T_lds[j * 1024 + l];
        #pragma unroll
        for (int v = 0; v < 16; ++v)
            Tj[v * 64] = A[v & 3] + C[v >> 2];
    }
    __syncthreads();

    // Main loop: 32 words per thread, strict > with ascending w => first-wins
    const uint4* cw4 = reinterpret_cast<const uint4*>(cw_lds);
    const float* Tl = &T_lds[l];
    float bestf = -INFINITY;
    uint32_t bestw = 0;
    const uint32_t wbase = blockIdx.x * WPB + wv * 32;

    #pragma unroll
    for (int wq = 0; wq < 8; ++wq) {
        uint4 c4 = cw4[wv * 8 + wq];
        #pragma unroll
        for (int e = 0; e < 4; ++e) {
            uint32_t cw = (e == 0) ? c4.x : (e == 1) ? c4.y : (e == 2) ? c4.z : c4.w;
            float r0 = Tl[0 * 1024 + ((cw >> 0) & 15u) * 64];
            float r1 = Tl[1 * 1024 + ((cw >> 4) & 15u) * 64];
            float r2 = Tl[2 * 1024 + ((cw >> 8) & 15u) * 64];
            float r3 = Tl[3 * 1024 + ((cw >> 12) & 15u) * 64];
            float r4 = Tl[4 * 1024 + ((cw >> 16) & 15u) * 64];
            float r5 = Tl[5 * 1024 + ((cw >> 20) & 15u) * 64];
            float r6 = Tl[6 * 1024 + ((cw >> 24) & 15u) * 64];
            float r7 = Tl[7 * 1024 + ((cw >> 28) & 15u) * 64];
            float c = ((r0 + r1) + (r2 + r3)) + ((r4 + r5) + (r6 + r7));
            uint32_t w = wbase + wq * 4 + e;
            bool g = c > bestf;
            bestw = g ? w : bestw;
            bestf = g ? c : bestf;
        }
    }

    bestf_lds[wv * 64 + l] = bestf;
    bestw_lds[wv * 64 + l] = bestw;
    __syncthreads();

    // Merge 4 waves (ascending w ranges; strict > keeps lower w) + store key
    if (tid < B) {
        float f = bestf_lds[tid];
        uint32_t w = bestw_lds[tid];
        #pragma unroll
        for (int v = 1; v < 4; ++v) {
            float f2 = bestf_lds[v * 64 + tid];
            uint32_t w2 = bestw_lds[v * 64 + tid];
            bool g = f2 > f;
            w = g ? w2 : w;
            f = g ? f2 : f;
        }
        uint32_t bits = __float_as_uint(f);
        uint32_t mono = (bits & 0x80000000u) ? ~bits : (bits | 0x80000000u);
        u64 key = ((u64)mono << 16) | (u64)(0xFFFFu - w);
        ws_keys[tid * BLOCKS + blockIdx.x] = key;
    }
}

// Kernel 2: one wave per batch; coalesced 16B loads; u64 max; decode bits.
__global__ __launch_bounds__(64) void mdd_reduce(
    const u64* __restrict__ ws_keys,   // [B][BLOCKS]
    float* __restrict__ out)           // [B][K]
{
    const int b = blockIdx.x;
    const int lane = threadIdx.x;
    const ulonglong2* p = reinterpret_cast<const ulonglong2*>(ws_keys + (size_t)b * BLOCKS);

    u64 m = 0;
    #pragma unroll
    for (int i = 0; i < 4; ++i) {
        ulonglong2 v = p[i * 64 + lane];
        u64 a = v.x > v.y ? v.x : v.y;
        m = a > m ? a : m;
    }
    #pragma unroll
    for (int off = 32; off > 0; off >>= 1) {
        u64 o = __shfl_xor(m, off, 64);
        m = o > m ? o : m;
    }
    uint32_t w = 0xFFFFu - (uint32_t)(m & 0xFFFFu);
    if (lane < K) out[b * K + lane] = (float)((w >> lane) & 1u);
}

extern "C" void kernel_launch(void* const* d_in, const int* in_sizes, int n_in,
                              void* d_out, int out_size, void* d_ws, size_t ws_size,
                              hipStream_t stream) {
    const float* noisy = (const float*)d_in[0];
    const int* G = (const int*)d_in[1];
    const float* sigma2 = (const float*)d_in[2];
    float* out = (float*)d_out;
    u64* ws_keys = (u64*)d_ws;

    (void)in_sizes; (void)n_in; (void)out_size; (void)ws_size;

    mdd_corr<<<BLOCKS, 256, 0, stream>>>(noisy, G, sigma2, ws_keys);
    mdd_reduce<<<B, 64, 0, stream>>>(ws_keys, out);
}